// Round 1
// baseline (13.631 us; speedup 1.0000x reference)
//
#include <hip/hip_runtime.h>
#include <math.h>

#define NB 128
#define IMS 64
#define NTHREADS 256
#define NA 10     // L_Q actions
#define NO 8      // fc outputs

// One block per batch element. Handles both w==0 fast path (scan is a no-op)
// and the general path (full value iteration in LDS).
__global__ __launch_bounds__(NTHREADS)
void vin_kernel(const float* __restrict__ input_view,  // [128][2][64][64]
                const int*   __restrict__ state_x,     // [128]
                const int*   __restrict__ state_y,     // [128]
                const int*   __restrict__ k_ptr,       // scalar
                const float* __restrict__ h_w,         // [150][2][3][3]
                const float* __restrict__ h_b,         // [150]
                const float* __restrict__ r_w,         // [150] (1,150,1,1)
                const float* __restrict__ q_w,         // [10][1][3][3]
                const float* __restrict__ w,           // [10][1][3][3]
                const float* __restrict__ fc_w,        // [8][10]
                float* __restrict__ out)               // [2][128][8] flat
{
    const int b   = blockIdx.x;
    const int tid = threadIdx.x;

    __shared__ float eff_w[19];      // 18 taps [c*9+dy*3+dx] + bias at [18]
    __shared__ float qw_s[90];
    __shared__ float w_s[90];
    __shared__ int   w_any_s;
    __shared__ float r_patch[9];     // fast path 3x3 r neighborhood
    __shared__ float qout_s[NA];

    // general-path buffers (zero-padded borders for SAME conv)
    __shared__ float r_s[66][66];
    __shared__ float va[66][66];
    __shared__ float vb[66][66];

    if (tid == 0) w_any_s = 0;
    if (tid >= 32 && tid < 122) {        // load q_w / w, detect w != 0
        int t = tid - 32;
        qw_s[t] = q_w[t];
        float wv = w[t];
        w_s[t] = wv;
        if (wv != 0.0f) atomicOr(&w_any_s, 1);
    }
    // collapse (h_w, h_b, r_w) -> effective 2x3x3 conv + bias (19 threads)
    if (tid < 19) {
        float acc = 0.0f;
        if (tid < 18) {
            #pragma unroll 10
            for (int c = 0; c < 150; ++c) acc += r_w[c] * h_w[c * 18 + tid];
        } else {
            #pragma unroll 10
            for (int c = 0; c < 150; ++c) acc += r_w[c] * h_b[c];
        }
        eff_w[tid] = acc;
    }
    __syncthreads();

    const bool w_any = (w_any_s != 0);
    const int  sx = state_x[b];
    const int  sy = state_y[b];
    const float* inb = input_view + (size_t)b * 2 * IMS * IMS;

    if (!w_any) {
        // ---- FAST PATH: conv(v,w)==0 -> q == q_init; only need r 3x3 patch ----
        if (tid < 9) {
            const int di = tid / 3, dj = tid % 3;
            const int ri = sx + di - 1, rj = sy + dj - 1;
            float val = 0.0f;                       // SAME padding of q conv
            if (ri >= 0 && ri < IMS && rj >= 0 && rj < IMS) {
                float acc = eff_w[18];
                #pragma unroll
                for (int c = 0; c < 2; ++c)
                    #pragma unroll
                    for (int dy = 0; dy < 3; ++dy) {
                        const int y = ri + dy - 1;
                        if (y < 0 || y >= IMS) continue;
                        #pragma unroll
                        for (int dx = 0; dx < 3; ++dx) {
                            const int x = rj + dx - 1;
                            if (x < 0 || x >= IMS) continue;
                            acc += inb[(c * IMS + y) * IMS + x] * eff_w[c * 9 + dy * 3 + dx];
                        }
                    }
                val = acc;
            }
            r_patch[tid] = val;
        }
        __syncthreads();
        if (tid < NA) {
            float acc = 0.0f;
            #pragma unroll
            for (int t = 0; t < 9; ++t) acc += qw_s[tid * 9 + t] * r_patch[t];
            qout_s[tid] = acc;
        }
        __syncthreads();
    } else {
        // ---- GENERAL PATH: full r image + k-step value iteration in LDS ----
        const int k = *k_ptr;
        for (int p = tid; p < 66 * 66; p += NTHREADS) {
            ((float*)r_s)[p] = 0.0f;
            ((float*)va)[p]  = 0.0f;
            ((float*)vb)[p]  = 0.0f;
        }
        __syncthreads();

        // r (effective 3x3 conv of input), interior
        for (int p = tid; p < IMS * IMS; p += NTHREADS) {
            const int i = p >> 6, j = p & 63;
            float acc = eff_w[18];
            for (int c = 0; c < 2; ++c)
                for (int dy = 0; dy < 3; ++dy) {
                    const int y = i + dy - 1;
                    if (y < 0 || y >= IMS) continue;
                    for (int dx = 0; dx < 3; ++dx) {
                        const int x = j + dx - 1;
                        if (x < 0 || x >= IMS) continue;
                        acc += inb[(c * IMS + y) * IMS + x] * eff_w[c * 9 + dy * 3 + dx];
                    }
                }
            r_s[i + 1][j + 1] = acc;
        }
        __syncthreads();

        // v0 = max_a conv(r, q_w)
        for (int p = tid; p < IMS * IMS; p += NTHREADS) {
            const int i = p >> 6, j = p & 63;
            float v = -INFINITY;
            for (int a = 0; a < NA; ++a) {
                float acc = 0.0f;
                #pragma unroll
                for (int t = 0; t < 9; ++t)
                    acc += qw_s[a * 9 + t] * r_s[i + t / 3][j + t % 3];
                v = fmaxf(v, acc);
            }
            va[i + 1][j + 1] = v;
        }
        __syncthreads();

        float (*cur)[66] = va;
        float (*nxt)[66] = vb;
        for (int it = 0; it < k; ++it) {
            for (int p = tid; p < IMS * IMS; p += NTHREADS) {
                const int i = p >> 6, j = p & 63;
                float v = -INFINITY;
                for (int a = 0; a < NA; ++a) {
                    float acc = 0.0f;
                    #pragma unroll
                    for (int t = 0; t < 9; ++t)
                        acc += qw_s[a * 9 + t] * r_s[i + t / 3][j + t % 3]
                             + w_s[a * 9 + t]  * cur[i + t / 3][j + t % 3];
                    v = fmaxf(v, acc);
                }
                nxt[i + 1][j + 1] = v;
            }
            __syncthreads();
            float (*tmp)[66] = cur; cur = nxt; nxt = tmp;
        }

        // final q at (sx, sy)
        if (tid < NA) {
            float acc = 0.0f;
            #pragma unroll
            for (int t = 0; t < 9; ++t)
                acc += qw_s[tid * 9 + t] * r_s[sx + t / 3][sy + t % 3]
                     + w_s[tid * 9 + t]  * cur[sx + t / 3][sy + t % 3];
            qout_s[tid] = acc;
        }
        __syncthreads();
    }

    // logits = qout @ fc_w^T ; softmax
    if (tid == 0) {
        float logits[NO];
        float m = -INFINITY;
        #pragma unroll
        for (int o = 0; o < NO; ++o) {
            float acc = 0.0f;
            #pragma unroll
            for (int a = 0; a < NA; ++a) acc += fc_w[o * NA + a] * qout_s[a];
            logits[o] = acc;
            m = fmaxf(m, acc);
        }
        float s = 0.0f;
        float e[NO];
        #pragma unroll
        for (int o = 0; o < NO; ++o) { e[o] = expf(logits[o] - m); s += e[o]; }
        const float inv = 1.0f / s;
        #pragma unroll
        for (int o = 0; o < NO; ++o) {
            out[b * NO + o] = logits[o];                 // logits
            out[NB * NO + b * NO + o] = e[o] * inv;      // softmax
        }
    }
}

extern "C" void kernel_launch(void* const* d_in, const int* in_sizes, int n_in,
                              void* d_out, int out_size, void* d_ws, size_t ws_size,
                              hipStream_t stream) {
    const float* input_view = (const float*)d_in[0];
    const int*   state_x    = (const int*)d_in[1];
    const int*   state_y    = (const int*)d_in[2];
    const int*   k_ptr      = (const int*)d_in[3];
    const float* h_w        = (const float*)d_in[4];
    const float* h_b        = (const float*)d_in[5];
    const float* r_w        = (const float*)d_in[6];
    const float* q_w        = (const float*)d_in[7];
    const float* w          = (const float*)d_in[8];
    const float* fc_w       = (const float*)d_in[9];
    float* out = (float*)d_out;

    vin_kernel<<<NB, NTHREADS, 0, stream>>>(input_view, state_x, state_y, k_ptr,
                                            h_w, h_b, r_w, q_w, w, fc_w, out);
}